// Round 21
// baseline (24.634 us; speedup 1.0000x reference)
//
#include <hip/hip_runtime.h>

typedef __attribute__((ext_vector_type(4))) float f32x4;
typedef __attribute__((ext_vector_type(16))) float f32x16;
typedef __attribute__((ext_vector_type(8))) _Float16 f16x8;

#define D_ 64
#define K_ 512

// 2-limb f16 (a = hi + lo, 22 mantissa bits) on mfma_f32_32x32x16_f16.
// K-space = 128 limbs in 8 k-blocks of 16: kb 0-3 = hi(dims 16kb..16kb+15),
// kb 4-7 = lo. Operand slot (lane>>5, s) holds dim-pos (lane>>5)*8 + s —
// IDENTICAL builder for entries (A) and queries (B) => within-k-block
// permutation cancels in A.B (validated r15-r20: absmax 0.0).
// Queries NEGATED; acc seeded with 0.5||e||^2: score = 0.5||e||^2 - c.e
// (lo.lo dropped ~1.5e-5; hi.lo terms required — r19).
// C/D (HW m74/m101): col = lane&31 = query, row = (reg&3)+8*(reg>>2)+4*(lane>>5).
//
// r21 = r18 split into TWO PANELS of 128 queries per block (same grid/work):
// ef-build amortized once; panel-0's gather/write stores issue before panel-1's
// MFMA loop and drain underneath it; panel-1's staging loads issued before
// panel-0's loop. Attacks the serial head/tail of r18 (last untried overlap).
__global__ __launch_bounds__(512, 2)
void vq_fused(const float* __restrict__ codes,
              const float* __restrict__ codebook,
              float* __restrict__ out) {
  __shared__ _Float16 Af[2 * 16384];     // 64 KB: [panel][qtile*4096+kb*512+ph*256+qr*8]
  __shared__ float esq_s[K_];            // 2 KB
  __shared__ float smin[2][8][128];      // 8 KB
  __shared__ int   simin[2][8][128];     // 8 KB
  __shared__ int   best[2][128];         // 1 KB

  const int t = threadIdx.x;
  const int w = t >> 6, l = t & 63;
  const int l32 = l & 31, lhi = l >> 5;
  const long long qb = (long long)blockIdx.x * 256;

  // ---- panel-0 query loads first (thread -> query ql, dims dq*16..+15) ----
  const int ql = t >> 2, dq = t & 3;
  f32x4 av0[4], av1[4];
  {
    const float* s0 = codes + (qb + ql) * D_ + dq * 16;
#pragma unroll
    for (int g = 0; g < 4; ++g) av0[g] = *(const f32x4*)(s0 + 4 * g);
  }

  // ---- build ef frags + 0.5||e||^2 ONCE (wave owns entries 64w..64w+63) ----
  f16x8 ef[2][8];                        // [tile][kb] kb0-3 hi, kb4-7 lo
#pragma unroll
  for (int i = 0; i < 2; ++i) {
    const int e = w * 64 + i * 32 + l32;
    float es = 0.f;
#pragma unroll
    for (int kb = 0; kb < 4; ++kb) {
      const float* src = codebook + e * D_ + kb * 16 + lhi * 8;
      f32x4 v0 = *(const f32x4*)src;
      f32x4 v1 = *(const f32x4*)(src + 4);
#pragma unroll
      for (int s = 0; s < 8; ++s) {
        float a = (s < 4) ? v0[s & 3] : v1[s & 3];
        es += a * a;
        _Float16 h = (_Float16)a;
        ef[i][kb][s] = h;
        ef[i][4 + kb][s] = (_Float16)(a - (float)h);
      }
    }
    es += __shfl_xor(es, 32, 64);
    if (lhi == 0) esq_s[e] = 0.5f * es;
  }

  // staging: thread's 16 dims = k-block dq (hi) and dq+4 (lo); slot (ph,s) = dim ph*8+s
  auto stage = [&](int p, const f32x4* av) {
    _Float16* dst = Af + p * 16384 + (ql >> 5) * 4096 + dq * 512 + (ql & 31) * 8;
#pragma unroll
    for (int ph = 0; ph < 2; ++ph) {
      f16x8 wh, wl;
#pragma unroll
      for (int s = 0; s < 8; ++s) {
        float na = -av[ph * 2 + (s >> 2)][s & 3];
        _Float16 h = (_Float16)na;
        wh[s] = h;
        wl[s] = (_Float16)(na - (float)h);
      }
      *(f16x8*)(dst + ph * 256) = wh;          // hi k-block dq
      *(f16x8*)(dst + 2048 + ph * 256) = wl;   // lo k-block dq+4
    }
  };

  stage(0, av0);
  __syncthreads();                       // B1: Af[0] + esq_s ready

  // panel-1 loads issued NOW; consumed after loop(p0) (HBM hides under MFMA)
  {
    const float* s1 = codes + (qb + 128 + ql) * D_ + dq * 16;
#pragma unroll
    for (int g = 0; g < 4; ++g) av1[g] = *(const f32x4*)(s1 + 4 * g);
  }

  f32x4 esqr[2][4];
#pragma unroll
  for (int i = 0; i < 2; ++i)
#pragma unroll
    for (int g = 0; g < 4; ++g)
      esqr[i][g] = *(const f32x4*)(esq_s + w * 64 + i * 32 + 8 * g + 4 * lhi);

  auto finish = [&](const f32x16& a0, const f32x16& a1, int p, int qt) {
    float mv = 3.4e38f; int mi = 0;
#pragma unroll
    for (int g = 0; g < 4; ++g)
#pragma unroll
      for (int r = 0; r < 4; ++r) {
        const int e0 = w * 64 + 8 * g + 4 * lhi + r;
        if (a0[4 * g + r] < mv) { mv = a0[4 * g + r]; mi = e0; }
      }
#pragma unroll
    for (int g = 0; g < 4; ++g)
#pragma unroll
      for (int r = 0; r < 4; ++r) {
        const int e1 = w * 64 + 32 + 8 * g + 4 * lhi + r;
        if (a1[4 * g + r] < mv) { mv = a1[4 * g + r]; mi = e1; }
      }
    float ov = __shfl_xor(mv, 32, 64);
    int oi = __shfl_xor(mi, 32, 64);
    if (ov < mv || (ov == mv && oi < mi)) { mv = ov; mi = oi; }
    if (lhi == 0) {
      smin[p][w][qt * 32 + l32] = mv;
      simin[p][w][qt * 32 + l32] = mi;
    }
  };

  auto mfma24 = [&](const f16x8* qf, f32x16& a0, f32x16& a1) {
#pragma unroll
    for (int g = 0; g < 4; ++g)
#pragma unroll
      for (int r = 0; r < 4; ++r) {
        a0[4 * g + r] = esqr[0][g][r];
        a1[4 * g + r] = esqr[1][g][r];
      }
    __builtin_amdgcn_s_setprio(1);
#pragma unroll
    for (int kb = 0; kb < 4; ++kb) {     // eh . (-ch)
      a0 = __builtin_amdgcn_mfma_f32_32x32x16_f16(ef[0][kb], qf[kb], a0, 0, 0, 0);
      a1 = __builtin_amdgcn_mfma_f32_32x32x16_f16(ef[1][kb], qf[kb], a1, 0, 0, 0);
    }
#pragma unroll
    for (int kb = 0; kb < 4; ++kb) {     // eh . (-cl)
      a0 = __builtin_amdgcn_mfma_f32_32x32x16_f16(ef[0][kb], qf[4 + kb], a0, 0, 0, 0);
      a1 = __builtin_amdgcn_mfma_f32_32x32x16_f16(ef[1][kb], qf[4 + kb], a1, 0, 0, 0);
    }
#pragma unroll
    for (int kb = 0; kb < 4; ++kb) {     // el . (-ch)
      a0 = __builtin_amdgcn_mfma_f32_32x32x16_f16(ef[0][4 + kb], qf[kb], a0, 0, 0, 0);
      a1 = __builtin_amdgcn_mfma_f32_32x32x16_f16(ef[1][4 + kb], qf[kb], a1, 0, 0, 0);
    }
    __builtin_amdgcn_s_setprio(0);
  };

  // software-pipelined 4-qt sweep over one panel
  auto loop_panel = [&](int p) {
    const _Float16* qbase = Af + p * 16384 + lhi * 256 + l32 * 8;
    f16x8 qfA[8], qfB[8];
#pragma unroll
    for (int kb = 0; kb < 8; ++kb)
      qfA[kb] = *(const f16x8*)(qbase + 0 * 4096 + kb * 512);
#pragma unroll
    for (int qt = 0; qt < 4; qt += 2) {
#pragma unroll
      for (int kb = 0; kb < 8; ++kb)     // prefetch qt+1 before qt's burst
        qfB[kb] = *(const f16x8*)(qbase + (qt + 1) * 4096 + kb * 512);
      f32x16 a0, a1;
      mfma24(qfA, a0, a1);
      if (qt + 2 < 4) {
#pragma unroll
        for (int kb = 0; kb < 8; ++kb)
          qfA[kb] = *(const f16x8*)(qbase + (qt + 2) * 4096 + kb * 512);
      }
      finish(a0, a1, p, qt);
      f32x16 b0, b1;
      mfma24(qfB, b0, b1);
      finish(b0, b1, p, qt + 1);
    }
  };

  auto combine = [&](int p) {            // t<128; disjoint ascending entry ranges
    if (t < 128) {
      float bv = smin[p][0][t]; int bi = simin[p][0][t];
#pragma unroll
      for (int ww = 1; ww < 8; ++ww) {
        float v = smin[p][ww][t]; int ii = simin[p][ww][t];
        if (v < bv || (v == bv && ii < bi)) { bv = v; bi = ii; }
      }
      best[p][t] = bi;
    }
  };

  auto gather = [&](int p) {             // 2048 f32x4; stores drain under next phase
#pragma unroll
    for (int i2 = 0; i2 < 4; ++i2) {
      const int f = t + 512 * i2;
      const int q = f >> 4, g = f & 15;
      const int e = best[p][q];
      f32x4 v = *(const f32x4*)(codebook + e * D_ + g * 4);
      __builtin_nontemporal_store(v, (f32x4*)(out + (qb + p * 128 + q) * D_ + g * 4));
    }
  };

  loop_panel(0);                         // barrier-free sweep, panel 0
  stage(1, av1);                         // Af[1] distinct from Af[0]: no race
  __syncthreads();                       // B2: smin[0] + Af[1] ready
  combine(0);
  __syncthreads();                       // B3: best[0] ready
  gather(0);                             // stores issue, drain under loop(p1)
  loop_panel(1);
  __syncthreads();                       // B4: smin[1] ready
  combine(1);
  __syncthreads();                       // B5: best[1] ready
  gather(1);
}

extern "C" void kernel_launch(void* const* d_in, const int* in_sizes, int n_in,
                              void* d_out, int out_size, void* d_ws, size_t ws_size,
                              hipStream_t stream) {
  const float* codes = (const float*)d_in[0];
  const float* codebook = (const float*)d_in[1];
  float* out = (float*)d_out;
  const int Q = in_sizes[0] / D_;        // 65536
  const int grid = Q / 256;              // 256
  vq_fused<<<grid, 512, 0, stream>>>(codes, codebook, out);
}